// Round 5
// baseline (277.499 us; speedup 1.0000x reference)
//
#include <hip/hip_runtime.h>
#include <math.h>

// GAT: 1024 graphs (B*S), N=256, F=O=64, H=1. One block (4 waves) per graph.
// Round-5: 38.9KB LDS -> 4 blocks/CU (16 waves). Mask bitmap eliminated:
// validity read from adj in transposed (coalesced) pattern with 1-tile
// prefetch. Half-size time-multiplexed alpha buffer. invl via shfl.
// One __syncthreads total.

constexpr int NN = 256;
constexpr int FF = 64;
constexpr int OO = 64;

// LDS layout (bytes)
constexpr int OFF_HT  = 0;      // hT[64][256] f16, byte = o*512 + ((2j)^((o&7)<<4))
constexpr int OFF_AL  = 32768;  // al[4 waves][32 rows][40 B] = 5120
constexpr int OFF_AS  = 37888;  // a_s f32[256] = 1024
constexpr int OFF_RED = 38912;  // red f32[4]
constexpr int SMEM_TOTAL = 38928;   // -> 4 blocks/CU (<=40960)

typedef _Float16 half4 __attribute__((ext_vector_type(4)));
typedef float f32x4 __attribute__((ext_vector_type(4)));

__global__ __launch_bounds__(256, 4) void gat_fused(
    const float* __restrict__ x,        // [BS, N, F]
    const int*   __restrict__ adj,      // [BS, N, N]  adj[j][i]!=0 => edge j->i
    const float* __restrict__ W,        // [F, O]
    const float* __restrict__ att_src,  // [O]
    const float* __restrict__ att_dst,  // [O]
    const float* __restrict__ bias,     // [O]
    float* __restrict__ out)            // [BS, N, O]
{
    __shared__ __align__(16) unsigned char smem[SMEM_TOTAL];
    float* as_s  = (float*)(smem + OFF_AS);
    float* red_s = (float*)(smem + OFF_RED);

    const int tid  = threadIdx.x;       // target node i
    const int bs   = blockIdx.x;
    const int lane = tid & 63;
    const int wv   = tid >> 6;

    const float* xg   = x + (size_t)bs * NN * FF;
    const int*   adjg = adj + (size_t)bs * NN * NN;
    float*       outg = out + (size_t)bs * NN * OO;

    // ---- Phase A: h row i = x_i @ W (fp32); scores; hT f16 swizzled ----
    float acc[OO];
    #pragma unroll
    for (int o = 0; o < OO; ++o) acc[o] = 0.f;

    const float4* xv = reinterpret_cast<const float4*>(xg + tid * FF);
    const float4* Wv = reinterpret_cast<const float4*>(W);
    for (int k4 = 0; k4 < FF / 4; ++k4) {
        float4 xq = xv[k4];
        float xs[4] = {xq.x, xq.y, xq.z, xq.w};
        #pragma unroll
        for (int kk = 0; kk < 4; ++kk) {
            float xk = xs[kk];
            const float4* wrow = Wv + (k4 * 4 + kk) * (OO / 4);
            #pragma unroll
            for (int o4 = 0; o4 < OO / 4; ++o4) {
                float4 w = wrow[o4];   // wave-uniform -> scalar loads
                acc[o4 * 4 + 0] = fmaf(xk, w.x, acc[o4 * 4 + 0]);
                acc[o4 * 4 + 1] = fmaf(xk, w.y, acc[o4 * 4 + 1]);
                acc[o4 * 4 + 2] = fmaf(xk, w.z, acc[o4 * 4 + 2]);
                acc[o4 * 4 + 3] = fmaf(xk, w.w, acc[o4 * 4 + 3]);
            }
        }
    }

    float as_i = 0.f, ad_i = 0.f;
    {
        const float4* sv = reinterpret_cast<const float4*>(att_src);
        const float4* dv = reinterpret_cast<const float4*>(att_dst);
        #pragma unroll
        for (int o4 = 0; o4 < OO / 4; ++o4) {
            float4 a = sv[o4], d = dv[o4];
            as_i += acc[o4*4+0]*a.x + acc[o4*4+1]*a.y + acc[o4*4+2]*a.z + acc[o4*4+3]*a.w;
            ad_i += acc[o4*4+0]*d.x + acc[o4*4+1]*d.y + acc[o4*4+2]*d.z + acc[o4*4+3]*d.w;
        }
    }
    as_s[tid] = as_i;
    // hT[o][tid] with byte ^= ((o&7)<<4) swizzle
    #pragma unroll
    for (int o = 0; o < OO; ++o) {
        int boff = o * 512 + ((2 * tid) ^ ((o & 7) << 4));
        *(_Float16*)(smem + OFF_HT + boff) = (_Float16)acc[o];
    }

    // Block-wide max of a_s (softmax shift upper bound)
    float vmax = as_i;
    #pragma unroll
    for (int off = 32; off > 0; off >>= 1)
        vmax = fmaxf(vmax, __shfl_xor(vmax, off));
    if (lane == 0) red_s[wv] = vmax;

    __syncthreads();   // the ONLY barrier: hT, as_s, red visible

    const float smax = fmaxf(fmaxf(red_s[0], red_s[1]), fmaxf(red_s[2], red_s[3]));
    float mm = ad_i + smax;
    mm = fmaxf(mm, 0.2f * mm);               // >= leaky(ad_i + as_j) for ALL j
    const float adm = ad_i - mm;             // u  = adm + as_j
    const float c2  = fmaf(0.2f, ad_i, -mm); // v  = fma(0.2, as_j, c2)

    const int r = lane & 15;
    const int g = lane >> 4;

    // alpha buffer addressing (per-wave 32-row region, time-multiplexed)
    const int alw   = OFF_AL + wv * 1280;
    const int wbase = alw + (tid & 31) * 40;     // this thread's write row
    const bool hi   = (tid & 32) != 0;           // lanes 32..63 -> subphase B
    const int afb0  = alw + r * 40 + g * 8;      // A-frag read, rows 0..15
    const int afb1  = alw + (16 + r) * 40 + g * 8;

    // hT B-frag bases (round-4 swizzle decomposition)
    const int lo = (g * 8) ^ ((r & 1) << 4);
    const int xh = ((r >> 1) & 3) * 32;
    int bfb[4];
    #pragma unroll
    for (int nc = 0; nc < 4; ++nc) bfb[nc] = OFF_HT + (nc * 16 + r) * 512 + lo;

    f32x4 dacc[4][4];
    #pragma unroll
    for (int c = 0; c < 4; ++c)
        #pragma unroll
        for (int nc = 0; nc < 4; ++nc)
            dacc[c][nc] = (f32x4){0.f, 0.f, 0.f, 0.f};

    float lacc[4] = {0.f, 0.f, 0.f, 0.f};

    // adj validity: thread i reads column i (coalesced across lanes)
    const int* adjcol = adjg + tid;
    int av[16];
    #pragma unroll
    for (int e = 0; e < 16; ++e) av[e] = adjcol[e * NN];   // tile 0

    // ---- Pass 2: 16 j-tiles of 16, barrier-free ----
    #pragma unroll
    for (int t = 0; t < 16; ++t) {
        // prefetch next tile's adj column slice
        int avn[16];
        if (t < 15) {
            #pragma unroll
            for (int e = 0; e < 16; ++e)
                avn[e] = adjcol[(t + 1) * 16 * NN + e * NN];
        }

        // p (unnormalized alpha, f16) for this thread's row, j = t*16 .. +15
        half4 pq[4];
        #pragma unroll
        for (int q = 0; q < 4; ++q) {
            float4 a4 = *(const float4*)&as_s[t * 16 + q * 4];
            float as4[4] = {a4.x, a4.y, a4.z, a4.w};
            half4 hv;
            #pragma unroll
            for (int e = 0; e < 4; ++e) {
                const int j = t * 16 + q * 4 + e;
                float aj = as4[e];
                float u  = adm + aj;
                float vv = fmaf(0.2f, aj, c2);
                float ev = fmaxf(u, vv);            // leaky(score) - m  (<= 0)
                float pf = __expf(ev);
                bool valid = (av[q * 4 + e] != 0) || (j == tid);  // self-loop
                pf = valid ? pf : 0.f;
                lacc[e] += pf;
                hv[e] = (_Float16)pf;
            }
            pq[q] = hv;
        }

        // B-fragments for this tile (shared by all c-chunks)
        half4 bf[4];
        const int kx = (t * 32) ^ xh;
        #pragma unroll
        for (int nc = 0; nc < 4; ++nc)
            bf[nc] = *(const half4*)(smem + bfb[nc] + kx);

        // subphase A: lanes 0..31 stage rows 0..31
        if (!hi) {
            #pragma unroll
            for (int q = 0; q < 4; ++q)
                *(half4*)(smem + wbase + q * 8) = pq[q];
        }
        asm volatile("" ::: "memory");
        #pragma unroll
        for (int c = 0; c < 2; ++c) {
            half4 af = *(const half4*)(smem + (c ? afb1 : afb0));
            #pragma unroll
            for (int nc = 0; nc < 4; ++nc)
                dacc[c][nc] = __builtin_amdgcn_mfma_f32_16x16x16f16(
                    af, bf[nc], dacc[c][nc], 0, 0, 0);
        }
        asm volatile("" ::: "memory");
        // subphase B: lanes 32..63 reuse the same 32 rows for rows 32..63
        if (hi) {
            #pragma unroll
            for (int q = 0; q < 4; ++q)
                *(half4*)(smem + wbase + q * 8) = pq[q];
        }
        asm volatile("" ::: "memory");
        #pragma unroll
        for (int c = 2; c < 4; ++c) {
            half4 af = *(const half4*)(smem + ((c & 1) ? afb1 : afb0));
            #pragma unroll
            for (int nc = 0; nc < 4; ++nc)
                dacc[c][nc] = __builtin_amdgcn_mfma_f32_16x16x16f16(
                    af, bf[nc], dacc[c][nc], 0, 0, 0);
        }
        asm volatile("" ::: "memory");

        if (t < 15) {
            #pragma unroll
            for (int e = 0; e < 16; ++e) av[e] = avn[e];
        }
    }

    const float l = (lacc[0] + lacc[1]) + (lacc[2] + lacc[3]);
    const float invl = 1.0f / l;     // self-loop term > 0

    // ---- Epilogue: normalize (invl via shfl from owner lane) + bias ----
    float bl[4];
    #pragma unroll
    for (int nc = 0; nc < 4; ++nc) bl[nc] = bias[nc * 16 + r];

    #pragma unroll
    for (int c = 0; c < 4; ++c) {
        #pragma unroll
        for (int q = 0; q < 4; ++q) {
            const int rsel = c * 16 + g * 4 + q;     // owner lane of this row
            float ir = __shfl(invl, rsel, 64);
            const int i_row = wv * 64 + rsel;
            float* orow = outg + (size_t)i_row * OO;
            #pragma unroll
            for (int nc = 0; nc < 4; ++nc)
                orow[nc * 16 + r] = fmaf(dacc[c][nc][q], ir, bl[nc]);
        }
    }
}

extern "C" void kernel_launch(void* const* d_in, const int* in_sizes, int n_in,
                              void* d_out, int out_size, void* d_ws, size_t ws_size,
                              hipStream_t stream) {
    const float* x        = (const float*)d_in[0];
    const int*   adj      = (const int*)  d_in[1];
    const float* W        = (const float*)d_in[2];
    const float* att_src  = (const float*)d_in[3];
    const float* att_dst  = (const float*)d_in[4];
    const float* bias     = (const float*)d_in[5];
    float*       out      = (float*)d_out;

    dim3 grid(1024);
    dim3 block(256);
    hipLaunchKernelGGL(gat_fused, grid, block, 0, stream,
                       x, adj, W, att_src, att_dst, bias, out);
}